// Round 4
// baseline (2042.485 us; speedup 1.0000x reference)
//
#include <hip/hip_runtime.h>
#include <hip/hip_bf16.h>
#include <math.h>

#define L 2048
#define HDIM 2048
#define HV 32
#define HK 16
#define DK 128
#define DV 128
#define KS 4
#define KEY_DIM 2048
#define VALUE_DIM 4096
#define CONV_DIM 8192
#define QKVZ_N 12288
#define EPS 1e-6f

typedef __attribute__((ext_vector_type(8))) short short8v;   // 8 bf16 = 4 VGPRs
typedef __attribute__((ext_vector_type(4))) float f32x4;

__device__ __forceinline__ float silu_f(float x) { return x / (1.f + __expf(-x)); }

// RNE fp32 -> bf16 (bit pattern), and back. Inputs are finite (no NaN handling).
__device__ __forceinline__ ushort f2bf(float v) {
  unsigned u = __builtin_bit_cast(unsigned, v);
  unsigned r = (u + 0x7FFFu + ((u >> 16) & 1u)) >> 16;
  return (ushort)r;
}
__device__ __forceinline__ float bf2f(ushort b) {
  unsigned u = ((unsigned)b) << 16;
  return __builtin_bit_cast(float, u);
}

// ---------------- split fp32 -> bf16 hi/lo, elementwise ----------------
__global__ __launch_bounds__(256) void split_f32_bf16(const float* __restrict__ x,
                                                      ushort* __restrict__ hi,
                                                      ushort* __restrict__ lo,
                                                      int n4) {
  const int i = blockIdx.x * 256 + threadIdx.x;
  if (i >= n4) return;
  float4 v = *(const float4*)&x[(size_t)i * 4];
  ushort4 h, l;
  h.x = f2bf(v.x); l.x = f2bf(v.x - bf2f(h.x));
  h.y = f2bf(v.y); l.y = f2bf(v.y - bf2f(h.y));
  h.z = f2bf(v.z); l.z = f2bf(v.z - bf2f(h.z));
  h.w = f2bf(v.w); l.w = f2bf(v.w - bf2f(h.w));
  *(ushort4*)&hi[(size_t)i * 4] = h;
  *(ushort4*)&lo[(size_t)i * 4] = l;
}

// ---------------- transpose + split: W[R][C] fp32 -> T[C][R] bf16 hi/lo ---------
__global__ __launch_bounds__(256) void transpose_split(const float* __restrict__ W,
                                                       ushort* __restrict__ Thi,
                                                       ushort* __restrict__ Tlo,
                                                       int R, int Ccols) {
  __shared__ float tile[32][33];
  const int tx = threadIdx.x & 7, ty = threadIdx.x >> 3;   // 8 x 32
  const int c0 = blockIdx.x * 32, r0 = blockIdx.y * 32;
  float4 v = *(const float4*)&W[(size_t)(r0 + ty) * Ccols + c0 + tx * 4];
  tile[tx * 4 + 0][ty] = v.x;
  tile[tx * 4 + 1][ty] = v.y;
  tile[tx * 4 + 2][ty] = v.z;
  tile[tx * 4 + 3][ty] = v.w;
  __syncthreads();
  float a0 = tile[ty][tx * 4 + 0];
  float a1 = tile[ty][tx * 4 + 1];
  float a2 = tile[ty][tx * 4 + 2];
  float a3 = tile[ty][tx * 4 + 3];
  ushort4 h, l;
  h.x = f2bf(a0); l.x = f2bf(a0 - bf2f(h.x));
  h.y = f2bf(a1); l.y = f2bf(a1 - bf2f(h.y));
  h.z = f2bf(a2); l.z = f2bf(a2 - bf2f(h.z));
  h.w = f2bf(a3); l.w = f2bf(a3 - bf2f(h.w));
  const size_t o = (size_t)(c0 + ty) * R + r0 + tx * 4;
  *(ushort4*)&Thi[o] = h;
  *(ushort4*)&Tlo[o] = l;
}

// ---------------- split-bf16 MFMA GEMM: C[M][N] = A[M][K] * B[N][K]^T ----------
// A,B given as bf16 hi/lo pairs, row-major with K contiguous. 128x128 tile,
// BK=32, 4 waves (each 64x64 out), global_load_lds(16B) staging, 2-barrier loop.
// 3 MFMA passes per k-tile: hi*hi + hi*lo + lo*hi  (~16-bit effective mantissa).
__global__ __launch_bounds__(256) void mfma_gemm_split(
    const ushort* __restrict__ Ahi, const ushort* __restrict__ Alo,
    const ushort* __restrict__ Bhi, const ushort* __restrict__ Blo,
    float* __restrict__ C, int M, int N, int K) {
  __shared__ ushort lds[16384];          // As_hi|As_lo|Bs_hi|Bs_lo, each [128][32]
  ushort* As_hi = lds;
  ushort* As_lo = lds + 4096;
  ushort* Bs_hi = lds + 8192;
  ushort* Bs_lo = lds + 12288;
  const int tid = threadIdx.x;
  const int w = tid >> 6, l = tid & 63;
  const int wr = w >> 1, wc = w & 1;
  const int fl = l & 15, fh = l >> 4;
  const int m0 = blockIdx.y * 128, n0 = blockIdx.x * 128;

  f32x4 acc[4][4];
#pragma unroll
  for (int m = 0; m < 4; m++)
#pragma unroll
    for (int n = 0; n < 4; n++) acc[m][n] = (f32x4){0.f, 0.f, 0.f, 0.f};

  for (int kt = 0; kt < K; kt += 32) {
    __syncthreads();
#pragma unroll
    for (int i = 0; i < 2; i++) {
      // chunk c covers 16B of a [128][32] bf16 tile: row = c>>2, k-offset (c&3)*8
      const int cb = i * 256 + w * 64;       // wave-uniform base chunk
      const int c = cb + l;
      const int row = c >> 2;
      const int k8 = (c & 3) * 8;
      const size_t aoff = (size_t)(m0 + row) * K + kt + k8;
      const size_t boff = (size_t)(n0 + row) * K + kt + k8;
      __builtin_amdgcn_global_load_lds((const __attribute__((address_space(1))) void*)(Ahi + aoff),
                                       (__attribute__((address_space(3))) void*)(As_hi + cb * 8), 16, 0, 0);
      __builtin_amdgcn_global_load_lds((const __attribute__((address_space(1))) void*)(Alo + aoff),
                                       (__attribute__((address_space(3))) void*)(As_lo + cb * 8), 16, 0, 0);
      __builtin_amdgcn_global_load_lds((const __attribute__((address_space(1))) void*)(Bhi + boff),
                                       (__attribute__((address_space(3))) void*)(Bs_hi + cb * 8), 16, 0, 0);
      __builtin_amdgcn_global_load_lds((const __attribute__((address_space(1))) void*)(Blo + boff),
                                       (__attribute__((address_space(3))) void*)(Bs_lo + cb * 8), 16, 0, 0);
    }
    __syncthreads();

    short8v ah[4], al[4];
#pragma unroll
    for (int m = 0; m < 4; m++) {
      const int r = wr * 64 + m * 16 + fl;
      ah[m] = *(const short8v*)(As_hi + r * 32 + fh * 8);
      al[m] = *(const short8v*)(As_lo + r * 32 + fh * 8);
    }
#pragma unroll
    for (int n = 0; n < 4; n++) {
      const int r = wc * 64 + n * 16 + fl;
      const short8v bh = *(const short8v*)(Bs_hi + r * 32 + fh * 8);
      const short8v bl = *(const short8v*)(Bs_lo + r * 32 + fh * 8);
#pragma unroll
      for (int m = 0; m < 4; m++) {
        acc[m][n] = __builtin_amdgcn_mfma_f32_16x16x32_bf16(ah[m], bh, acc[m][n], 0, 0, 0);
        acc[m][n] = __builtin_amdgcn_mfma_f32_16x16x32_bf16(ah[m], bl, acc[m][n], 0, 0, 0);
        acc[m][n] = __builtin_amdgcn_mfma_f32_16x16x32_bf16(al[m], bh, acc[m][n], 0, 0, 0);
      }
    }
  }

  // C/D layout (HW-verified m89): col = lane&15, row = (lane>>4)*4 + j
#pragma unroll
  for (int m = 0; m < 4; m++)
#pragma unroll
    for (int n = 0; n < 4; n++)
#pragma unroll
      for (int j = 0; j < 4; j++) {
        const int row = m0 + wr * 64 + m * 16 + fh * 4 + j;
        const int col = n0 + wc * 64 + n * 16 + fl;
        C[(size_t)row * N + col] = acc[m][n][j];
      }
}

// ---------------- small GEMM for ba = hidden @ W_ba (N=64) ----------------
__global__ __launch_bounds__(256) void ba_gemm(const float* __restrict__ hs,
                                               const float* __restrict__ Wba,
                                               float* __restrict__ ba) {
  __shared__ float hrow[2048];
  __shared__ float part[4][64];
  const int t = blockIdx.x;
  const int tid = threadIdx.x;
  const float* hp = hs + (size_t)t * HDIM;
  *(float4*)&hrow[tid * 8]     = *(const float4*)&hp[tid * 8];
  *(float4*)&hrow[tid * 8 + 4] = *(const float4*)&hp[tid * 8 + 4];
  __syncthreads();
  const int c = tid & 63, p = tid >> 6;
  float acc = 0.f;
  const float* wp = Wba + (size_t)(p * 512) * 64 + c;
  for (int k = 0; k < 512; k++) acc = fmaf(hrow[p * 512 + k], wp[(size_t)k * 64], acc);
  part[p][c] = acc;
  __syncthreads();
  if (tid < 64) {
    float r = part[0][tid] + part[1][tid] + part[2][tid] + part[3][tid];
    ba[(size_t)t * 64 + tid] = r;
  }
}

// ---------------- causal depthwise conv (KS=4) + silu ----------------
__global__ __launch_bounds__(256) void conv_silu(const float* __restrict__ proj,
                                                 const float* __restrict__ cw,
                                                 float* __restrict__ out) {
  const int idx = blockIdx.x * 256 + threadIdx.x;  // L * (8192/4)
  const int t = idx >> 11;
  const int c = (idx & 2047) * 4;
  float4 w0 = *(const float4*)&cw[(c + 0) * 4];
  float4 w1 = *(const float4*)&cw[(c + 1) * 4];
  float4 w2 = *(const float4*)&cw[(c + 2) * 4];
  float4 w3 = *(const float4*)&cw[(c + 3) * 4];
  const float4 zero = make_float4(0.f, 0.f, 0.f, 0.f);
  float4 x0 = (t - 3 >= 0) ? *(const float4*)&proj[(size_t)(t - 3) * QKVZ_N + c] : zero;
  float4 x1 = (t - 2 >= 0) ? *(const float4*)&proj[(size_t)(t - 2) * QKVZ_N + c] : zero;
  float4 x2 = (t - 1 >= 0) ? *(const float4*)&proj[(size_t)(t - 1) * QKVZ_N + c] : zero;
  float4 x3 = *(const float4*)&proj[(size_t)t * QKVZ_N + c];
  float4 r;
  r.x = x0.x * w0.x + x1.x * w0.y + x2.x * w0.z + x3.x * w0.w;
  r.y = x0.y * w1.x + x1.y * w1.y + x2.y * w1.z + x3.y * w1.w;
  r.z = x0.z * w2.x + x1.z * w2.y + x2.z * w2.z + x3.z * w2.w;
  r.w = x0.w * w3.x + x1.w * w3.y + x2.w * w3.z + x3.w * w3.w;
  r.x = silu_f(r.x); r.y = silu_f(r.y); r.z = silu_f(r.z); r.w = silu_f(r.w);
  *(float4*)&out[(size_t)t * CONV_DIM + c] = r;
}

// ---------------- in-place l2norm of q,k rows (+ q scale) ----------------
__global__ __launch_bounds__(256) void l2norm_qk(float* __restrict__ conv) {
  const int row = blockIdx.x * 4 + (threadIdx.x >> 6);  // L*32 rows (16 q + 16 k per t)
  const int lane = threadIdx.x & 63;
  const int t = row >> 5;
  const int rem = row & 31;               // 0..15 q-heads, 16..31 k-heads
  const size_t base = (size_t)t * CONV_DIM + (size_t)rem * 128;
  float2 x = *(float2*)&conv[base + lane * 2];
  float ss = x.x * x.x + x.y * x.y;
  ss += __shfl_xor(ss, 1);
  ss += __shfl_xor(ss, 2);
  ss += __shfl_xor(ss, 4);
  ss += __shfl_xor(ss, 8);
  ss += __shfl_xor(ss, 16);
  ss += __shfl_xor(ss, 32);
  float sc = rsqrtf(ss + EPS);
  if (rem < 16) sc *= 0.08838834764831843f;  // DK^-0.5
  x.x *= sc;
  x.y *= sc;
  *(float2*)&conv[base + lane * 2] = x;
}

// ---------------- per-(t,h) gate params ----------------
__global__ __launch_bounds__(256) void gb_kernel(const float* __restrict__ ba,
                                                 const float* __restrict__ dtb,
                                                 const float* __restrict__ Alog,
                                                 float* __restrict__ g,
                                                 float* __restrict__ beta) {
  const int idx = blockIdx.x * 256 + threadIdx.x;  // L*32
  const int t = idx >> 5, h = idx & 31;
  const float b = ba[(size_t)t * 64 + h];
  const float a = ba[(size_t)t * 64 + 32 + h];
  beta[idx] = 1.f / (1.f + __expf(-b));
  const float x = a + dtb[h];
  const float sp = (x > 20.f) ? x : log1pf(__expf(x));
  g[idx] = -__expf(Alog[h]) * sp;
}

// ---------------- sequential delta-rule scan ----------------
// One column of S (per head h, value-dim v) is an independent recurrence.
// 16 lanes/column (8 state floats each), 4 columns/wave, 16 columns/block.
__global__ __launch_bounds__(256) void deltanet_scan(const float* __restrict__ conv,
                                                     const float* __restrict__ garr,
                                                     const float* __restrict__ barr,
                                                     float* __restrict__ core) {
  const int blk = blockIdx.x;       // 32 heads * 8 v-groups
  const int h = blk >> 3;
  const int vbase = (blk & 7) * 16;
  const int kh = h >> 1;
  const int tid = threadIdx.x;
  const int w = tid >> 6;
  const int grp = (tid & 63) >> 4;
  const int l = tid & 15;
  const int v = vbase + w * 4 + grp;

  const float* qp = conv + (size_t)kh * 128 + l * 8;
  const float* kp = conv + 2048 + (size_t)kh * 128 + l * 8;
  const float* vp = conv + 4096 + (size_t)h * 128 + v;

  float s[8];
#pragma unroll
  for (int j = 0; j < 8; j++) s[j] = 0.f;

  float4 kA = *(const float4*)(kp);
  float4 kB = *(const float4*)(kp + 4);
  float4 qA = *(const float4*)(qp);
  float4 qB = *(const float4*)(qp + 4);
  float vt = *vp;
  float gt = garr[h];
  float bt = barr[h];

  for (int t = 0; t < L; t++) {
    const int tn = (t + 1 < L) ? t + 1 : t;
    const size_t off = (size_t)tn * CONV_DIM;
    float4 kA2 = *(const float4*)(kp + off);
    float4 kB2 = *(const float4*)(kp + off + 4);
    float4 qA2 = *(const float4*)(qp + off);
    float4 qB2 = *(const float4*)(qp + off + 4);
    float vt2 = vp[off];
    float gt2 = garr[(size_t)tn * 32 + h];
    float bt2 = barr[(size_t)tn * 32 + h];

    const float e = __expf(gt);
    float dk = s[0] * kA.x;
    dk = fmaf(s[1], kA.y, dk);
    dk = fmaf(s[2], kA.z, dk);
    dk = fmaf(s[3], kA.w, dk);
    dk = fmaf(s[4], kB.x, dk);
    dk = fmaf(s[5], kB.y, dk);
    dk = fmaf(s[6], kB.z, dk);
    dk = fmaf(s[7], kB.w, dk);
    dk += __shfl_xor(dk, 1);
    dk += __shfl_xor(dk, 2);
    dk += __shfl_xor(dk, 4);
    dk += __shfl_xor(dk, 8);
    const float delta = (vt - e * dk) * bt;
    s[0] = fmaf(s[0], e, kA.x * delta);
    s[1] = fmaf(s[1], e, kA.y * delta);
    s[2] = fmaf(s[2], e, kA.z * delta);
    s[3] = fmaf(s[3], e, kA.w * delta);
    s[4] = fmaf(s[4], e, kB.x * delta);
    s[5] = fmaf(s[5], e, kB.y * delta);
    s[6] = fmaf(s[6], e, kB.z * delta);
    s[7] = fmaf(s[7], e, kB.w * delta);
    float dq = s[0] * qA.x;
    dq = fmaf(s[1], qA.y, dq);
    dq = fmaf(s[2], qA.z, dq);
    dq = fmaf(s[3], qA.w, dq);
    dq = fmaf(s[4], qB.x, dq);
    dq = fmaf(s[5], qB.y, dq);
    dq = fmaf(s[6], qB.z, dq);
    dq = fmaf(s[7], qB.w, dq);
    dq += __shfl_xor(dq, 1);
    dq += __shfl_xor(dq, 2);
    dq += __shfl_xor(dq, 4);
    dq += __shfl_xor(dq, 8);
    if (l == 0) core[(size_t)(t * 32 + h) * 128 + v] = dq;

    kA = kA2; kB = kB2; qA = qA2; qB = qB2;
    vt = vt2; gt = gt2; bt = bt2;
  }
}

// ---------------- RMSNorm * norm_w * silu(z) -> split bf16 hi/lo ----------------
__global__ __launch_bounds__(256) void post_kernel(const float* __restrict__ core,
                                                   const float* __restrict__ proj,
                                                   const float* __restrict__ normw,
                                                   ushort* __restrict__ ghi,
                                                   ushort* __restrict__ glo) {
  const int row = blockIdx.x * 4 + (threadIdx.x >> 6);  // L*32
  const int lane = threadIdx.x & 63;
  const int t = row >> 5, h = row & 31;
  const float* cp = core + (size_t)row * 128;
  float2 c = *(float2*)&cp[lane * 2];
  float ss = c.x * c.x + c.y * c.y;
  ss += __shfl_xor(ss, 1);
  ss += __shfl_xor(ss, 2);
  ss += __shfl_xor(ss, 4);
  ss += __shfl_xor(ss, 8);
  ss += __shfl_xor(ss, 16);
  ss += __shfl_xor(ss, 32);
  const float sc = rsqrtf(ss * (1.f / 128.f) + EPS);
  float2 nw = *(float2*)&normw[lane * 2];
  const float* zp = proj + (size_t)t * QKVZ_N + CONV_DIM + (size_t)h * 128;
  float2 z = *(float2*)&zp[lane * 2];
  const float o0 = c.x * sc * nw.x * silu_f(z.x);
  const float o1 = c.y * sc * nw.y * silu_f(z.y);
  ushort2 hh, ll;
  hh.x = f2bf(o0); ll.x = f2bf(o0 - bf2f(hh.x));
  hh.y = f2bf(o1); ll.y = f2bf(o1 - bf2f(hh.y));
  *(ushort2*)&ghi[(size_t)row * 128 + lane * 2] = hh;
  *(ushort2*)&glo[(size_t)row * 128 + lane * 2] = ll;
}

extern "C" void kernel_launch(void* const* d_in, const int* in_sizes, int n_in,
                              void* d_out, int out_size, void* d_ws, size_t ws_size,
                              hipStream_t stream) {
  const float* hs    = (const float*)d_in[0];
  const float* Wqkvz = (const float*)d_in[1];
  const float* Wba   = (const float*)d_in[2];
  const float* convw = (const float*)d_in[3];
  const float* dtb   = (const float*)d_in[4];
  const float* Alog  = (const float*)d_in[5];
  const float* normw = (const float*)d_in[6];
  const float* Wout  = (const float*)d_in[7];
  float* out = (float*)d_out;

  // workspace layout (floats), heavily aliased; total ~236 MB
  float* ws_f = (float*)d_ws;
  float* proj = ws_f;                         // 25165824 f (L x QKVZ_N fp32)
  float* r1   = ws_f + 25165824;              // 25165824 f
  float* r2   = r1 + 25165824;                // 8388608 f
  float* ba   = r2 + 8388608;                 // 131072 f
  float* g    = ba + 131072;                  // 65536 f
  float* beta = g + 65536;                    // 65536 f
  // r1: Wt_hi|Wt_lo during GEMM1; conv|core afterwards (Wt dead)
  ushort* Wt_hi = (ushort*)r1;                // 25165824 bf16
  ushort* Wt_lo = Wt_hi + 25165824;
  float* conv = r1;                           // 16777216 f
  float* core = r1 + 16777216;                // 8388608 f
  // r2: hs_hi|hs_lo during GEMM1; gated_hi|gated_lo afterwards
  ushort* hs_hi = (ushort*)r2;                // 4194304 bf16
  ushort* hs_lo = hs_hi + 4194304;
  ushort* gated_hi = (ushort*)r2;             // 8388608 bf16
  ushort* gated_lo = gated_hi + 8388608;
  // Wout transpose into proj region (proj dead after post_kernel)
  ushort* Wot_hi = (ushort*)proj;             // 8388608 bf16
  ushort* Wot_lo = Wot_hi + 8388608;

  split_f32_bf16<<<4096, 256, 0, stream>>>(hs, hs_hi, hs_lo, 1048576);
  transpose_split<<<dim3(QKVZ_N / 32, HDIM / 32), 256, 0, stream>>>(Wqkvz, Wt_hi, Wt_lo, HDIM, QKVZ_N);
  mfma_gemm_split<<<dim3(QKVZ_N / 128, L / 128), 256, 0, stream>>>(hs_hi, hs_lo, Wt_hi, Wt_lo,
                                                                   proj, L, QKVZ_N, HDIM);
  ba_gemm<<<L, 256, 0, stream>>>(hs, Wba, ba);
  gb_kernel<<<(L * 32) / 256, 256, 0, stream>>>(ba, dtb, Alog, g, beta);
  conv_silu<<<(L * (CONV_DIM / 4)) / 256, 256, 0, stream>>>(proj, convw, conv);
  l2norm_qk<<<(L * 32) / 4, 256, 0, stream>>>(conv);
  deltanet_scan<<<256, 256, 0, stream>>>(conv, g, beta, core);
  post_kernel<<<(L * 32) / 4, 256, 0, stream>>>(core, proj, normw, gated_hi, gated_lo);
  transpose_split<<<dim3(HDIM / 32, VALUE_DIM / 32), 256, 0, stream>>>(Wout, Wot_hi, Wot_lo,
                                                                      VALUE_DIM, HDIM);
  mfma_gemm_split<<<dim3(HDIM / 128, L / 128), 256, 0, stream>>>(gated_hi, gated_lo, Wot_hi, Wot_lo,
                                                                 out, L, HDIM, VALUE_DIM);
}

// Round 5
// 1549.747 us; speedup vs baseline: 1.3179x; 1.3179x over previous
//
#include <hip/hip_runtime.h>
#include <hip/hip_bf16.h>
#include <math.h>

#define L 2048
#define HDIM 2048
#define HV 32
#define HK 16
#define DK 128
#define DV 128
#define KS 4
#define KEY_DIM 2048
#define VALUE_DIM 4096
#define CONV_DIM 8192
#define QKVZ_N 12288
#define EPS 1e-6f
#define CHUNK 16

typedef __attribute__((ext_vector_type(8))) short short8v;   // 8 bf16 = 4 VGPRs
typedef __attribute__((ext_vector_type(4))) float f32x4;

__device__ __forceinline__ float silu_f(float x) { return x / (1.f + __expf(-x)); }

// RNE fp32 -> bf16 (bit pattern), and back. Inputs are finite (no NaN handling).
__device__ __forceinline__ ushort f2bf(float v) {
  unsigned u = __builtin_bit_cast(unsigned, v);
  unsigned r = (u + 0x7FFFu + ((u >> 16) & 1u)) >> 16;
  return (ushort)r;
}
__device__ __forceinline__ float bf2f(ushort b) {
  unsigned u = ((unsigned)b) << 16;
  return __builtin_bit_cast(float, u);
}

// DPP rotate-add within each 16-lane row: x += rotate(x, CTRL). After levels
// 1,2,4,8 every lane of the 16-lane group holds the full group sum.
template <int CTRL>
__device__ __forceinline__ float dpp_rot_add(float x) {
  float y = __int_as_float(__builtin_amdgcn_update_dpp(
      __float_as_int(x), __float_as_int(x), CTRL, 0xF, 0xF, false));
  return x + y;
}
__device__ __forceinline__ float reduce16(float x) {
  x = dpp_rot_add<0x121>(x);  // row_ror:1
  x = dpp_rot_add<0x122>(x);  // row_ror:2
  x = dpp_rot_add<0x124>(x);  // row_ror:4
  x = dpp_rot_add<0x128>(x);  // row_ror:8
  return x;
}

// ---------------- split fp32 -> bf16 hi/lo, elementwise ----------------
__global__ __launch_bounds__(256) void split_f32_bf16(const float* __restrict__ x,
                                                      ushort* __restrict__ hi,
                                                      ushort* __restrict__ lo,
                                                      int n4) {
  const int i = blockIdx.x * 256 + threadIdx.x;
  if (i >= n4) return;
  float4 v = *(const float4*)&x[(size_t)i * 4];
  ushort4 h, l;
  h.x = f2bf(v.x); l.x = f2bf(v.x - bf2f(h.x));
  h.y = f2bf(v.y); l.y = f2bf(v.y - bf2f(h.y));
  h.z = f2bf(v.z); l.z = f2bf(v.z - bf2f(h.z));
  h.w = f2bf(v.w); l.w = f2bf(v.w - bf2f(h.w));
  *(ushort4*)&hi[(size_t)i * 4] = h;
  *(ushort4*)&lo[(size_t)i * 4] = l;
}

// ---------------- transpose + split: W[R][C] fp32 -> T[C][R] bf16 hi/lo ---------
__global__ __launch_bounds__(256) void transpose_split(const float* __restrict__ W,
                                                       ushort* __restrict__ Thi,
                                                       ushort* __restrict__ Tlo,
                                                       int R, int Ccols) {
  __shared__ float tile[32][33];
  const int tx = threadIdx.x & 7, ty = threadIdx.x >> 3;   // 8 x 32
  const int c0 = blockIdx.x * 32, r0 = blockIdx.y * 32;
  float4 v = *(const float4*)&W[(size_t)(r0 + ty) * Ccols + c0 + tx * 4];
  tile[tx * 4 + 0][ty] = v.x;
  tile[tx * 4 + 1][ty] = v.y;
  tile[tx * 4 + 2][ty] = v.z;
  tile[tx * 4 + 3][ty] = v.w;
  __syncthreads();
  float a0 = tile[ty][tx * 4 + 0];
  float a1 = tile[ty][tx * 4 + 1];
  float a2 = tile[ty][tx * 4 + 2];
  float a3 = tile[ty][tx * 4 + 3];
  ushort4 h, l;
  h.x = f2bf(a0); l.x = f2bf(a0 - bf2f(h.x));
  h.y = f2bf(a1); l.y = f2bf(a1 - bf2f(h.y));
  h.z = f2bf(a2); l.z = f2bf(a2 - bf2f(h.z));
  h.w = f2bf(a3); l.w = f2bf(a3 - bf2f(h.w));
  const size_t o = (size_t)(c0 + ty) * R + r0 + tx * 4;
  *(ushort4*)&Thi[o] = h;
  *(ushort4*)&Tlo[o] = l;
}

// ---------------- split-bf16 MFMA GEMM: C[M][N] = A[M][K] * B[N][K]^T ----------
__global__ __launch_bounds__(256) void mfma_gemm_split(
    const ushort* __restrict__ Ahi, const ushort* __restrict__ Alo,
    const ushort* __restrict__ Bhi, const ushort* __restrict__ Blo,
    float* __restrict__ C, int M, int N, int K) {
  __shared__ ushort lds[16384];          // As_hi|As_lo|Bs_hi|Bs_lo, each [128][32]
  ushort* As_hi = lds;
  ushort* As_lo = lds + 4096;
  ushort* Bs_hi = lds + 8192;
  ushort* Bs_lo = lds + 12288;
  const int tid = threadIdx.x;
  const int w = tid >> 6, l = tid & 63;
  const int wr = w >> 1, wc = w & 1;
  const int fl = l & 15, fh = l >> 4;
  const int m0 = blockIdx.y * 128, n0 = blockIdx.x * 128;

  f32x4 acc[4][4];
#pragma unroll
  for (int m = 0; m < 4; m++)
#pragma unroll
    for (int n = 0; n < 4; n++) acc[m][n] = (f32x4){0.f, 0.f, 0.f, 0.f};

  for (int kt = 0; kt < K; kt += 32) {
    __syncthreads();
#pragma unroll
    for (int i = 0; i < 2; i++) {
      const int cb = i * 256 + w * 64;       // wave-uniform base chunk
      const int c = cb + l;
      const int row = c >> 2;
      const int k8 = (c & 3) * 8;
      const size_t aoff = (size_t)(m0 + row) * K + kt + k8;
      const size_t boff = (size_t)(n0 + row) * K + kt + k8;
      __builtin_amdgcn_global_load_lds((const __attribute__((address_space(1))) void*)(Ahi + aoff),
                                       (__attribute__((address_space(3))) void*)(As_hi + cb * 8), 16, 0, 0);
      __builtin_amdgcn_global_load_lds((const __attribute__((address_space(1))) void*)(Alo + aoff),
                                       (__attribute__((address_space(3))) void*)(As_lo + cb * 8), 16, 0, 0);
      __builtin_amdgcn_global_load_lds((const __attribute__((address_space(1))) void*)(Bhi + boff),
                                       (__attribute__((address_space(3))) void*)(Bs_hi + cb * 8), 16, 0, 0);
      __builtin_amdgcn_global_load_lds((const __attribute__((address_space(1))) void*)(Blo + boff),
                                       (__attribute__((address_space(3))) void*)(Bs_lo + cb * 8), 16, 0, 0);
    }
    __syncthreads();

    short8v ah[4], al[4];
#pragma unroll
    for (int m = 0; m < 4; m++) {
      const int r = wr * 64 + m * 16 + fl;
      ah[m] = *(const short8v*)(As_hi + r * 32 + fh * 8);
      al[m] = *(const short8v*)(As_lo + r * 32 + fh * 8);
    }
#pragma unroll
    for (int n = 0; n < 4; n++) {
      const int r = wc * 64 + n * 16 + fl;
      const short8v bh = *(const short8v*)(Bs_hi + r * 32 + fh * 8);
      const short8v bl = *(const short8v*)(Bs_lo + r * 32 + fh * 8);
#pragma unroll
      for (int m = 0; m < 4; m++) {
        acc[m][n] = __builtin_amdgcn_mfma_f32_16x16x32_bf16(ah[m], bh, acc[m][n], 0, 0, 0);
        acc[m][n] = __builtin_amdgcn_mfma_f32_16x16x32_bf16(ah[m], bl, acc[m][n], 0, 0, 0);
        acc[m][n] = __builtin_amdgcn_mfma_f32_16x16x32_bf16(al[m], bh, acc[m][n], 0, 0, 0);
      }
    }
  }

#pragma unroll
  for (int m = 0; m < 4; m++)
#pragma unroll
    for (int n = 0; n < 4; n++)
#pragma unroll
      for (int j = 0; j < 4; j++) {
        const int row = m0 + wr * 64 + m * 16 + fh * 4 + j;
        const int col = n0 + wc * 64 + n * 16 + fl;
        C[(size_t)row * N + col] = acc[m][n][j];
      }
}

// ---------------- small GEMM for ba = hidden @ W_ba (N=64) ----------------
__global__ __launch_bounds__(256) void ba_gemm(const float* __restrict__ hs,
                                               const float* __restrict__ Wba,
                                               float* __restrict__ ba) {
  __shared__ float hrow[2048];
  __shared__ float part[4][64];
  const int t = blockIdx.x;
  const int tid = threadIdx.x;
  const float* hp = hs + (size_t)t * HDIM;
  *(float4*)&hrow[tid * 8]     = *(const float4*)&hp[tid * 8];
  *(float4*)&hrow[tid * 8 + 4] = *(const float4*)&hp[tid * 8 + 4];
  __syncthreads();
  const int c = tid & 63, p = tid >> 6;
  float acc = 0.f;
  const float* wp = Wba + (size_t)(p * 512) * 64 + c;
  for (int k = 0; k < 512; k++) acc = fmaf(hrow[p * 512 + k], wp[(size_t)k * 64], acc);
  part[p][c] = acc;
  __syncthreads();
  if (tid < 64) {
    float r = part[0][tid] + part[1][tid] + part[2][tid] + part[3][tid];
    ba[(size_t)t * 64 + tid] = r;
  }
}

// ---------------- causal depthwise conv (KS=4) + silu ----------------
__global__ __launch_bounds__(256) void conv_silu(const float* __restrict__ proj,
                                                 const float* __restrict__ cw,
                                                 float* __restrict__ out) {
  const int idx = blockIdx.x * 256 + threadIdx.x;  // L * (8192/4)
  const int t = idx >> 11;
  const int c = (idx & 2047) * 4;
  float4 w0 = *(const float4*)&cw[(c + 0) * 4];
  float4 w1 = *(const float4*)&cw[(c + 1) * 4];
  float4 w2 = *(const float4*)&cw[(c + 2) * 4];
  float4 w3 = *(const float4*)&cw[(c + 3) * 4];
  const float4 zero = make_float4(0.f, 0.f, 0.f, 0.f);
  float4 x0 = (t - 3 >= 0) ? *(const float4*)&proj[(size_t)(t - 3) * QKVZ_N + c] : zero;
  float4 x1 = (t - 2 >= 0) ? *(const float4*)&proj[(size_t)(t - 2) * QKVZ_N + c] : zero;
  float4 x2 = (t - 1 >= 0) ? *(const float4*)&proj[(size_t)(t - 1) * QKVZ_N + c] : zero;
  float4 x3 = *(const float4*)&proj[(size_t)t * QKVZ_N + c];
  float4 r;
  r.x = x0.x * w0.x + x1.x * w0.y + x2.x * w0.z + x3.x * w0.w;
  r.y = x0.y * w1.x + x1.y * w1.y + x2.y * w1.z + x3.y * w1.w;
  r.z = x0.z * w2.x + x1.z * w2.y + x2.z * w2.z + x3.z * w2.w;
  r.w = x0.w * w3.x + x1.w * w3.y + x2.w * w3.z + x3.w * w3.w;
  r.x = silu_f(r.x); r.y = silu_f(r.y); r.z = silu_f(r.z); r.w = silu_f(r.w);
  *(float4*)&out[(size_t)t * CONV_DIM + c] = r;
}

// ---------------- in-place l2norm of q,k rows (+ q scale) ----------------
__global__ __launch_bounds__(256) void l2norm_qk(float* __restrict__ conv) {
  const int row = blockIdx.x * 4 + (threadIdx.x >> 6);  // L*32 rows (16 q + 16 k per t)
  const int lane = threadIdx.x & 63;
  const int t = row >> 5;
  const int rem = row & 31;               // 0..15 q-heads, 16..31 k-heads
  const size_t base = (size_t)t * CONV_DIM + (size_t)rem * 128;
  float2 x = *(float2*)&conv[base + lane * 2];
  float ss = x.x * x.x + x.y * x.y;
  ss += __shfl_xor(ss, 1);
  ss += __shfl_xor(ss, 2);
  ss += __shfl_xor(ss, 4);
  ss += __shfl_xor(ss, 8);
  ss += __shfl_xor(ss, 16);
  ss += __shfl_xor(ss, 32);
  float sc = rsqrtf(ss + EPS);
  if (rem < 16) sc *= 0.08838834764831843f;  // DK^-0.5
  x.x *= sc;
  x.y *= sc;
  *(float2*)&conv[base + lane * 2] = x;
}

// ---------------- per-(t,h) gate params: beta = sigmoid(b), eg = exp(g) -------
__global__ __launch_bounds__(256) void gb_kernel(const float* __restrict__ ba,
                                                 const float* __restrict__ dtb,
                                                 const float* __restrict__ Alog,
                                                 float* __restrict__ eg,
                                                 float* __restrict__ beta) {
  const int idx = blockIdx.x * 256 + threadIdx.x;  // L*32
  const int t = idx >> 5, h = idx & 31;
  const float b = ba[(size_t)t * 64 + h];
  const float a = ba[(size_t)t * 64 + 32 + h];
  beta[idx] = 1.f / (1.f + __expf(-b));
  const float x = a + dtb[h];
  const float sp = (x > 20.f) ? x : log1pf(__expf(x));
  eg[idx] = __expf(-__expf(Alog[h]) * sp);   // exp(g), precomputed for the scan
}

// ---------------- sequential delta-rule scan (LDS chunk-staged) ----------------
// Per block: one head h, 16 v-columns. 16 lanes per column. Chunks of 16 steps
// are cooperatively staged into double-buffered LDS (T14: issue loads early,
// ds_write after compute). Reductions via DPP rotate-add (no LDS on the chain).
__global__ __launch_bounds__(256) void deltanet_scan(const float* __restrict__ conv,
                                                     const float* __restrict__ eg,
                                                     const float* __restrict__ barr,
                                                     float* __restrict__ core) {
  __shared__ float sQ[2][CHUNK][128];
  __shared__ float sK[2][CHUNK][128];
  __shared__ float sV[2][CHUNK][16];
  __shared__ float sG[2][CHUNK];
  __shared__ float sB[2][CHUNK];

  const int blk = blockIdx.x;       // 32 heads * 8 v-groups of 16 columns
  const int h = blk >> 3;
  const int vbase = (blk & 7) * 16;
  const int kh = h >> 1;
  const int tid = threadIdx.x;
  const int l = tid & 15;           // lane within column group (k-slice)
  const int cg = tid >> 4;          // column group 0..15
  const int v = vbase + cg;

  float s[8];
#pragma unroll
  for (int j = 0; j < 8; j++) s[j] = 0.f;

  float4 rr4[5];
  float rg = 0.f, rb = 0.f;

  // stage: 16 steps * (32 q + 32 k + 4 v) float4 chunks = 1088 items
#define STAGE_LOAD(T0)                                                          \
  {                                                                             \
    _Pragma("unroll")                                                           \
    for (int it = 0; it < 5; it++) {                                            \
      const int idx = tid + it * 256;                                           \
      if (idx < 1088) {                                                         \
        const int st = idx / 68;                                                \
        const int rr = idx - st * 68;                                           \
        const size_t toff = (size_t)((T0) + st) * CONV_DIM;                     \
        const float* srcp;                                                      \
        if (rr < 32)      srcp = conv + toff + (size_t)kh * 128 + rr * 4;       \
        else if (rr < 64) srcp = conv + toff + 2048 + (size_t)kh * 128 + (rr - 32) * 4; \
        else              srcp = conv + toff + 4096 + (size_t)h * 128 + vbase + (rr - 64) * 4; \
        rr4[it] = *(const float4*)srcp;                                         \
      }                                                                         \
    }                                                                           \
    if (tid < CHUNK)          rg = eg[(size_t)((T0) + tid) * 32 + h];           \
    else if (tid < 2 * CHUNK) rb = barr[(size_t)((T0) + tid - CHUNK) * 32 + h]; \
  }

#define STAGE_WRITE(B)                                                          \
  {                                                                             \
    _Pragma("unroll")                                                           \
    for (int it = 0; it < 5; it++) {                                            \
      const int idx = tid + it * 256;                                           \
      if (idx < 1088) {                                                         \
        const int st = idx / 68;                                                \
        const int rr = idx - st * 68;                                           \
        float* dstp;                                                            \
        if (rr < 32)      dstp = &sQ[B][st][rr * 4];                            \
        else if (rr < 64) dstp = &sK[B][st][(rr - 32) * 4];                     \
        else              dstp = &sV[B][st][(rr - 64) * 4];                     \
        *(float4*)dstp = rr4[it];                                               \
      }                                                                         \
    }                                                                           \
    if (tid < CHUNK)          sG[B][tid] = rg;                                  \
    else if (tid < 2 * CHUNK) sB[B][tid - CHUNK] = rb;                          \
  }

  // prologue: chunk 0 into buffer 0
  STAGE_LOAD(0);
  STAGE_WRITE(0);
  __syncthreads();

  int p = 0;
  for (int c = 0; c < L / CHUNK; c++) {
    const int t0n = (c + 1 < L / CHUNK) ? (c + 1) * CHUNK : c * CHUNK;  // clamped
    STAGE_LOAD(t0n);   // issue next chunk's globals; latency hides under compute

#pragma unroll 4
    for (int st = 0; st < CHUNK; st++) {
      const float4 k0 = *(const float4*)&sK[p][st][l * 8];
      const float4 k1 = *(const float4*)&sK[p][st][l * 8 + 4];
      const float4 q0 = *(const float4*)&sQ[p][st][l * 8];
      const float4 q1 = *(const float4*)&sQ[p][st][l * 8 + 4];
      const float vt = sV[p][st][cg];
      const float e  = sG[p][st];
      const float bt = sB[p][st];

      // dk = <s, k> : tree form (16cy chain) + DPP reduce
      float t0 = s[0] * k0.x, t1 = s[1] * k0.y, t2 = s[2] * k0.z, t3 = s[3] * k0.w;
      float t4 = s[4] * k1.x, t5 = s[5] * k1.y, t6 = s[6] * k1.z, t7 = s[7] * k1.w;
      float dk = ((t0 + t1) + (t2 + t3)) + ((t4 + t5) + (t6 + t7));
      dk = reduce16(dk);

      const float delta = fmaf(-e, dk, vt) * bt;

      s[0] = fmaf(s[0], e, k0.x * delta);
      s[1] = fmaf(s[1], e, k0.y * delta);
      s[2] = fmaf(s[2], e, k0.z * delta);
      s[3] = fmaf(s[3], e, k0.w * delta);
      s[4] = fmaf(s[4], e, k1.x * delta);
      s[5] = fmaf(s[5], e, k1.y * delta);
      s[6] = fmaf(s[6], e, k1.z * delta);
      s[7] = fmaf(s[7], e, k1.w * delta);

      // dq = <s_new, q> : off the critical chain, fma form (fewer instrs)
      float dq = s[0] * q0.x;
      dq = fmaf(s[1], q0.y, dq);
      dq = fmaf(s[2], q0.z, dq);
      dq = fmaf(s[3], q0.w, dq);
      dq = fmaf(s[4], q1.x, dq);
      dq = fmaf(s[5], q1.y, dq);
      dq = fmaf(s[6], q1.z, dq);
      dq = fmaf(s[7], q1.w, dq);
      dq = reduce16(dq);

      if (l == 0) core[(size_t)((c * CHUNK + st) * 32 + h) * 128 + v] = dq;
    }

    STAGE_WRITE(p ^ 1);   // waits vmcnt, writes next chunk
    __syncthreads();
    p ^= 1;
  }
#undef STAGE_LOAD
#undef STAGE_WRITE
}

// ---------------- RMSNorm * norm_w * silu(z) -> split bf16 hi/lo ----------------
__global__ __launch_bounds__(256) void post_kernel(const float* __restrict__ core,
                                                   const float* __restrict__ proj,
                                                   const float* __restrict__ normw,
                                                   ushort* __restrict__ ghi,
                                                   ushort* __restrict__ glo) {
  const int row = blockIdx.x * 4 + (threadIdx.x >> 6);  // L*32
  const int lane = threadIdx.x & 63;
  const int t = row >> 5, h = row & 31;
  const float* cp = core + (size_t)row * 128;
  float2 c = *(float2*)&cp[lane * 2];
  float ss = c.x * c.x + c.y * c.y;
  ss += __shfl_xor(ss, 1);
  ss += __shfl_xor(ss, 2);
  ss += __shfl_xor(ss, 4);
  ss += __shfl_xor(ss, 8);
  ss += __shfl_xor(ss, 16);
  ss += __shfl_xor(ss, 32);
  const float sc = rsqrtf(ss * (1.f / 128.f) + EPS);
  float2 nw = *(float2*)&normw[lane * 2];
  const float* zp = proj + (size_t)t * QKVZ_N + CONV_DIM + (size_t)h * 128;
  float2 z = *(float2*)&zp[lane * 2];
  const float o0 = c.x * sc * nw.x * silu_f(z.x);
  const float o1 = c.y * sc * nw.y * silu_f(z.y);
  ushort2 hh, ll;
  hh.x = f2bf(o0); ll.x = f2bf(o0 - bf2f(hh.x));
  hh.y = f2bf(o1); ll.y = f2bf(o1 - bf2f(hh.y));
  *(ushort2*)&ghi[(size_t)row * 128 + lane * 2] = hh;
  *(ushort2*)&glo[(size_t)row * 128 + lane * 2] = ll;
}

extern "C" void kernel_launch(void* const* d_in, const int* in_sizes, int n_in,
                              void* d_out, int out_size, void* d_ws, size_t ws_size,
                              hipStream_t stream) {
  const float* hs    = (const float*)d_in[0];
  const float* Wqkvz = (const float*)d_in[1];
  const float* Wba   = (const float*)d_in[2];
  const float* convw = (const float*)d_in[3];
  const float* dtb   = (const float*)d_in[4];
  const float* Alog  = (const float*)d_in[5];
  const float* normw = (const float*)d_in[6];
  const float* Wout  = (const float*)d_in[7];
  float* out = (float*)d_out;

  // workspace layout (floats), heavily aliased; total ~236 MB
  float* ws_f = (float*)d_ws;
  float* proj = ws_f;                         // 25165824 f (L x QKVZ_N fp32)
  float* r1   = ws_f + 25165824;              // 25165824 f
  float* r2   = r1 + 25165824;                // 8388608 f
  float* ba   = r2 + 8388608;                 // 131072 f
  float* g    = ba + 131072;                  // 65536 f (exp(g))
  float* beta = g + 65536;                    // 65536 f
  // r1: Wt_hi|Wt_lo during GEMM1; conv|core afterwards (Wt dead)
  ushort* Wt_hi = (ushort*)r1;                // 25165824 bf16
  ushort* Wt_lo = Wt_hi + 25165824;
  float* conv = r1;                           // 16777216 f
  float* core = r1 + 16777216;                // 8388608 f
  // r2: hs_hi|hs_lo during GEMM1; gated_hi|gated_lo afterwards
  ushort* hs_hi = (ushort*)r2;                // 4194304 bf16
  ushort* hs_lo = hs_hi + 4194304;
  ushort* gated_hi = (ushort*)r2;             // 8388608 bf16
  ushort* gated_lo = gated_hi + 8388608;
  // Wout transpose into proj region (proj dead after post_kernel)
  ushort* Wot_hi = (ushort*)proj;             // 8388608 bf16
  ushort* Wot_lo = Wot_hi + 8388608;

  split_f32_bf16<<<4096, 256, 0, stream>>>(hs, hs_hi, hs_lo, 1048576);
  transpose_split<<<dim3(QKVZ_N / 32, HDIM / 32), 256, 0, stream>>>(Wqkvz, Wt_hi, Wt_lo, HDIM, QKVZ_N);
  mfma_gemm_split<<<dim3(QKVZ_N / 128, L / 128), 256, 0, stream>>>(hs_hi, hs_lo, Wt_hi, Wt_lo,
                                                                   proj, L, QKVZ_N, HDIM);
  ba_gemm<<<L, 256, 0, stream>>>(hs, Wba, ba);
  gb_kernel<<<(L * 32) / 256, 256, 0, stream>>>(ba, dtb, Alog, g, beta);
  conv_silu<<<(L * (CONV_DIM / 4)) / 256, 256, 0, stream>>>(proj, convw, conv);
  l2norm_qk<<<(L * 32) / 4, 256, 0, stream>>>(conv);
  deltanet_scan<<<256, 256, 0, stream>>>(conv, g, beta, core);
  post_kernel<<<(L * 32) / 4, 256, 0, stream>>>(core, proj, normw, gated_hi, gated_lo);
  transpose_split<<<dim3(HDIM / 32, VALUE_DIM / 32), 256, 0, stream>>>(Wout, Wot_hi, Wot_lo,
                                                                      VALUE_DIM, HDIM);
  mfma_gemm_split<<<dim3(HDIM / 128, L / 128), 256, 0, stream>>>(gated_hi, gated_lo, Wot_hi, Wot_lo,
                                                                 out, L, HDIM, VALUE_DIM);
}